// Round 1
// baseline (653.323 us; speedup 1.0000x reference)
//
#include <hip/hip_runtime.h>

typedef unsigned int uint32;
typedef unsigned short u16;
typedef __attribute__((ext_vector_type(8))) short bf16x8;
typedef __attribute__((ext_vector_type(4))) float f32x4;

// ---------- helpers ----------
__device__ __forceinline__ u16 f2b(float f) {            // fp32 -> bf16 RNE
  uint32 u = __float_as_uint(f);
  u = (u + 0x7fffu + ((u >> 16) & 1u)) >> 16;
  return (u16)u;
}
__device__ __forceinline__ float b2f(u16 h) {
  return __uint_as_float(((uint32)h) << 16);
}
__device__ __forceinline__ void gl_lds16(const void* g, void* l) {
  typedef const __attribute__((address_space(1))) void* gp_t;
  typedef __attribute__((address_space(3))) void* lp_t;
  __builtin_amdgcn_global_load_lds((gp_t)g, (lp_t)l, 16, 0, 0);
}

// ---------- model constants ----------
#define L 1024
#define D 2048
#define NH 16
#define HD 128
#define VOCAB 32000
#define KV 2048
#define MASK_ID 31999

// ---------- ws layout (bytes) ----------
static constexpr long OFF_KV  = 0;                       // 2048*2048*2
static constexpr long OFF_WTQ = OFF_KV  + 8388608;
static constexpr long OFF_WTK = OFF_WTQ + 8388608;
static constexpr long OFF_WTV = OFF_WTK + 8388608;
static constexpr long OFF_WTO = OFF_WTV + 8388608;
static constexpr long OFF_Q   = OFF_WTO + 8388608;       // 1024*2048*2
static constexpr long OFF_K   = OFF_Q   + 4194304;       // 2048*2048*2
static constexpr long OFF_VT  = OFF_K   + 8388608;       // 2048*2048*2 (feature x token)
static constexpr long OFF_SC  = OFF_VT  + 8388608;       // 16*1024*2048*2
static constexpr long OFF_CTX = OFF_SC  + 67108864;      // 1024*2048*2
static constexpr long OFF_HID = OFF_CTX + 4194304;       // 1024*2048*2
static constexpr long OFF_LMT = OFF_HID + 4194304;       // 32000*2048*2
static constexpr long OFF_LOG = OFF_LMT + 131072000;     // 1024*32000*2
static constexpr long OFF_ROW = OFF_LOG + 65536000;      // 1024*2*4
static constexpr long WS_NEED = OFF_ROW + 8192;

// ---------- prep: build kv = [hidden_states ; noise_emb] in bf16 ----------
__global__ __launch_bounds__(256) void prep_kv(const float* __restrict__ hs,
                                               const int* __restrict__ ids,
                                               const float* __restrict__ emb,
                                               u16* __restrict__ kv) {
  int r = blockIdx.x;           // 0..2047
  int t = threadIdx.x;          // 256 threads * 8 elems
  const float* src;
  if (r < L) {
    src = hs + (long)r * D;
  } else {
    int p = r - L;
    int id = ((p & 15) == 0) ? ids[p] : MASK_ID;
    src = emb + (long)id * D;
  }
  float4 a = *(const float4*)(src + t * 8);
  float4 b = *(const float4*)(src + t * 8 + 4);
  u16* dst = kv + (long)r * D + t * 8;
  ushort4 o0, o1;
  o0.x = f2b(a.x); o0.y = f2b(a.y); o0.z = f2b(a.z); o0.w = f2b(a.w);
  o1.x = f2b(b.x); o1.y = f2b(b.y); o1.z = f2b(b.z); o1.w = f2b(b.w);
  *(ushort4*)dst = o0;
  *(ushort4*)(dst + 4) = o1;
}

// ---------- transpose + convert: W fp32 [K][N] -> WT bf16 [N][K] ----------
__global__ __launch_bounds__(256) void transpose_conv(const float* __restrict__ W,
                                                      u16* __restrict__ WT,
                                                      int Kd, int Nd) {
  __shared__ float tile[64][65];
  int n0 = blockIdx.x * 64;
  int k0 = blockIdx.y * 64;
  int t = threadIdx.x;
#pragma unroll
  for (int p = 0; p < 4; ++p) {
    int idx = p * 256 + t;
    int r = idx >> 4;           // k local 0..63
    int c = (idx & 15) << 2;    // n local 0..60
    float4 v = *(const float4*)(W + (long)(k0 + r) * Nd + n0 + c);
    tile[r][c] = v.x; tile[r][c + 1] = v.y; tile[r][c + 2] = v.z; tile[r][c + 3] = v.w;
  }
  __syncthreads();
#pragma unroll
  for (int p = 0; p < 4; ++p) {
    int idx = p * 256 + t;
    int rn = idx >> 4;          // n local
    int ck = (idx & 15) << 2;   // k local
    ushort4 o;
    o.x = f2b(tile[ck][rn]);
    o.y = f2b(tile[ck + 1][rn]);
    o.z = f2b(tile[ck + 2][rn]);
    o.w = f2b(tile[ck + 3][rn]);
    *(ushort4*)(WT + (long)(n0 + rn) * Kd + k0 + ck) = o;
  }
}

// ---------- 128x128 MFMA GEMM, A [M][K] bf16 row-major, BT [N][K] bf16 row-major ----------
// EPI: 0 = plain bf16 C, 1 = transposed bf16 store (CT[col][row]), 2 = scores (scale+mask)
#define EPI_PLAIN 0
#define EPI_TRANS 1
#define EPI_SCORES 2

template <int EPI>
__global__ __launch_bounds__(256) void gemm128(const u16* __restrict__ A, int lda, long aHead,
                                               const u16* __restrict__ BT, int ldb, long bHead,
                                               u16* __restrict__ C, int ldc, long cHead,
                                               int Kd) {
  __shared__ __align__(16) char lds[16384];
  char* a_lds = lds;
  char* b_lds = lds + 8192;
  int tid = threadIdx.x;
  int lane = tid & 63;
  int wave = tid >> 6;
  int wr = wave >> 1, wc = wave & 1;
  int h = blockIdx.z;
  long tm = (long)blockIdx.x * 128;
  long tn = (long)blockIdx.y * 128;
  const u16* Ap = A + (long)h * aHead + tm * lda;
  const u16* Bp = BT + (long)h * bHead + tn * ldb;

  int soff = tid * 16;          // staging flat byte offset (4 KB per round)
  int srow = soff >> 6;         // 64 B per row (32 bf16)
  int scol = (soff & 63) >> 1;  // elem col within 32
  char* aldsb = a_lds + wave * 1024;  // wave-uniform LDS base
  char* bldsb = b_lds + wave * 1024;

  f32x4 acc[4][4];
#pragma unroll
  for (int i = 0; i < 4; ++i)
#pragma unroll
    for (int j = 0; j < 4; ++j) acc[i][j] = (f32x4){0.f, 0.f, 0.f, 0.f};

  for (int k0 = 0; k0 < Kd; k0 += 32) {
#pragma unroll
    for (int r = 0; r < 2; ++r) {
      gl_lds16(Ap + (long)(srow + r * 64) * lda + k0 + scol, aldsb + r * 4096);
      gl_lds16(Bp + (long)(srow + r * 64) * ldb + k0 + scol, bldsb + r * 4096);
    }
    __syncthreads();
    bf16x8 af[4], bfr[4];
    int ka = (lane >> 4) << 4;  // byte offset of this lane's 8 k-elems
#pragma unroll
    for (int mi = 0; mi < 4; ++mi)
      af[mi] = *(const bf16x8*)(a_lds + (wr * 64 + mi * 16 + (lane & 15)) * 64 + ka);
#pragma unroll
    for (int ni = 0; ni < 4; ++ni)
      bfr[ni] = *(const bf16x8*)(b_lds + (wc * 64 + ni * 16 + (lane & 15)) * 64 + ka);
#pragma unroll
    for (int mi = 0; mi < 4; ++mi)
#pragma unroll
      for (int ni = 0; ni < 4; ++ni)
        acc[mi][ni] = __builtin_amdgcn_mfma_f32_16x16x32_bf16(af[mi], bfr[ni], acc[mi][ni], 0, 0, 0);
    __syncthreads();
  }

  long crow0 = tm + wr * 64 + ((lane >> 4) << 2);
  int ccol0 = wc * 64 + (lane & 15);
  u16* Cp = C + (long)h * cHead;
  const float scale = 0.08838834764831845f;  // 1/sqrt(128)
#pragma unroll
  for (int mi = 0; mi < 4; ++mi) {
#pragma unroll
    for (int ni = 0; ni < 4; ++ni) {
      long col = tn + ccol0 + ni * 16;
#pragma unroll
      for (int j = 0; j < 4; ++j) {
        long row = crow0 + mi * 16 + j;
        float v = acc[mi][ni][j];
        if (EPI == EPI_PLAIN) {
          Cp[row * ldc + col] = f2b(v);
        } else if (EPI == EPI_TRANS) {
          Cp[col * ldc + row] = f2b(v);
        } else {  // scores: row = query token, col = key slot (0..2047)
          int rb = (int)row >> 4;
          int cb = (int)col >> 4;
          bool vis = (col < 1024) ? (cb < rb) : ((cb - 64) == rb);
          Cp[row * ldc + col] = f2b(vis ? v * scale : -1e30f);
        }
      }
    }
  }
}

// ---------- row softmax over 2048 (in place, bf16) ----------
__global__ __launch_bounds__(256) void softmax_rows(u16* __restrict__ sc) {
  long row = blockIdx.x;  // 16*1024 rows
  u16* p = sc + row * 2048;
  int t = threadIdx.x;
  bf16x8 v = *(const bf16x8*)(p + t * 8);
  float f[8];
#pragma unroll
  for (int i = 0; i < 8; ++i) f[i] = b2f((u16)v[i]);
  float m = f[0];
#pragma unroll
  for (int i = 1; i < 8; ++i) m = fmaxf(m, f[i]);
  for (int off = 1; off < 64; off <<= 1) m = fmaxf(m, __shfl_xor(m, off));
  __shared__ float redm[4], reds[4];
  if ((t & 63) == 0) redm[t >> 6] = m;
  __syncthreads();
  m = fmaxf(fmaxf(redm[0], redm[1]), fmaxf(redm[2], redm[3]));
  float e[8];
  float s = 0.f;
#pragma unroll
  for (int i = 0; i < 8; ++i) { e[i] = __expf(f[i] - m); s += e[i]; }
  for (int off = 1; off < 64; off <<= 1) s += __shfl_xor(s, off);
  if ((t & 63) == 0) reds[t >> 6] = s;
  __syncthreads();
  s = reds[0] + reds[1] + reds[2] + reds[3];
  float inv = 1.f / s;
  bf16x8 o;
#pragma unroll
  for (int i = 0; i < 8; ++i) o[i] = (short)f2b(e[i] * inv);
  *(bf16x8*)(p + t * 8) = o;
}

// ---------- per-row CE + argmax over vocab ----------
__global__ __launch_bounds__(256) void row_ce(const u16* __restrict__ logits,
                                              const int* __restrict__ ids,
                                              float* __restrict__ rowbuf) {
  int row = blockIdx.x;
  const u16* p = logits + (long)row * VOCAB;
  int t = threadIdx.x;
  int lane = t & 63, w = t >> 6;
  float m = -1e30f;
  int am = VOCAB;
  for (int i = t * 8; i < VOCAB; i += 2048) {
    bf16x8 v = *(const bf16x8*)(p + i);
#pragma unroll
    for (int j = 0; j < 8; ++j) {
      float f = b2f((u16)v[j]);
      if (f > m) { m = f; am = i + j; }           // ascending per-thread -> first max kept
      else if (f == m && (i + j) < am) am = i + j;
    }
  }
  for (int off = 1; off < 64; off <<= 1) {
    float om = __shfl_xor(m, off);
    int oa = __shfl_xor(am, off);
    if (om > m || (om == m && oa < am)) { m = om; am = oa; }
  }
  __shared__ float smax[4]; __shared__ int sidx[4]; __shared__ float ssum[4];
  if (lane == 0) { smax[w] = m; sidx[w] = am; }
  __syncthreads();
  float gm = smax[0]; int gi = sidx[0];
#pragma unroll
  for (int q = 1; q < 4; ++q) {
    if (smax[q] > gm || (smax[q] == gm && sidx[q] < gi)) { gm = smax[q]; gi = sidx[q]; }
  }
  float s = 0.f;
  for (int i = t * 8; i < VOCAB; i += 2048) {
    bf16x8 v = *(const bf16x8*)(p + i);
#pragma unroll
    for (int j = 0; j < 8; ++j) s += __expf(b2f((u16)v[j]) - gm);
  }
  for (int off = 1; off < 64; off <<= 1) s += __shfl_xor(s, off);
  if (lane == 0) ssum[w] = s;
  __syncthreads();
  if (t == 0) {
    float gs = ssum[0] + ssum[1] + ssum[2] + ssum[3];
    int tgt = ids[row];
    float tl = b2f(p[tgt]);
    rowbuf[row * 2] = gm + logf(gs) - tl;          // CE
    rowbuf[row * 2 + 1] = (gi == tgt) ? 1.f : 0.f; // correct
  }
}

// ---------- final: masked mean loss + accuracy ----------
__global__ __launch_bounds__(256) void final_reduce(const float* __restrict__ rowbuf,
                                                    const float* __restrict__ loss_mask,
                                                    float* __restrict__ out) {
  int t = threadIdx.x;
  float ce = 0.f, cnt = 0.f, cor = 0.f;
  for (int r = t; r < L; r += 256) {
    bool valid = (r >= 16) && ((r & 15) != 0);
    float comb = loss_mask[r] * (valid ? 1.f : 0.f);
    if (comb > 1e-6f) {
      ce += rowbuf[r * 2];
      cor += rowbuf[r * 2 + 1];
      cnt += 1.f;
    }
  }
  for (int off = 1; off < 64; off <<= 1) {
    ce += __shfl_xor(ce, off);
    cnt += __shfl_xor(cnt, off);
    cor += __shfl_xor(cor, off);
  }
  __shared__ float s1[4], s2[4], s3[4];
  int lane = t & 63, w = t >> 6;
  if (lane == 0) { s1[w] = ce; s2[w] = cnt; s3[w] = cor; }
  __syncthreads();
  if (t == 0) {
    float C = s1[0] + s1[1] + s1[2] + s1[3];
    float N = s2[0] + s2[1] + s2[2] + s2[3];
    float R = s3[0] + s3[1] + s3[2] + s3[3];
    out[0] = C / N;
    out[1] = R / N;
  }
}

__global__ void ws_too_small(float* out, float mb) {
  if (threadIdx.x == 0) { out[0] = 1e6f + mb; out[1] = -1e6f; }
}

// ---------- launch ----------
extern "C" void kernel_launch(void* const* d_in, const int* in_sizes, int n_in,
                              void* d_out, int out_size, void* d_ws, size_t ws_size,
                              hipStream_t stream) {
  const int* ids = (const int*)d_in[0];
  const float* hs = (const float*)d_in[2];
  const float* lmask = (const float*)d_in[3];
  const float* emb = (const float*)d_in[4];
  const float* Wq = (const float*)d_in[5];
  const float* Wk = (const float*)d_in[6];
  const float* Wv = (const float*)d_in[7];
  const float* Wo = (const float*)d_in[8];
  const float* Wlm = (const float*)d_in[9];
  float* out = (float*)d_out;
  char* ws = (char*)d_ws;

  if (ws_size < (size_t)WS_NEED) {
    ws_too_small<<<1, 64, 0, stream>>>(out, (float)(ws_size >> 20));
    return;
  }

  u16* kv  = (u16*)(ws + OFF_KV);
  u16* wtq = (u16*)(ws + OFF_WTQ);
  u16* wtk = (u16*)(ws + OFF_WTK);
  u16* wtv = (u16*)(ws + OFF_WTV);
  u16* wto = (u16*)(ws + OFF_WTO);
  u16* qb  = (u16*)(ws + OFF_Q);
  u16* kb  = (u16*)(ws + OFF_K);
  u16* vt  = (u16*)(ws + OFF_VT);
  u16* sc  = (u16*)(ws + OFF_SC);
  u16* ctx = (u16*)(ws + OFF_CTX);
  u16* hid = (u16*)(ws + OFF_HID);
  u16* lmt = (u16*)(ws + OFF_LMT);
  u16* lgt = (u16*)(ws + OFF_LOG);
  float* rowbuf = (float*)(ws + OFF_ROW);

  prep_kv<<<2048, 256, 0, stream>>>(hs, ids, emb, kv);
  transpose_conv<<<dim3(32, 32), 256, 0, stream>>>(Wq, wtq, D, D);
  transpose_conv<<<dim3(32, 32), 256, 0, stream>>>(Wk, wtk, D, D);
  transpose_conv<<<dim3(32, 32), 256, 0, stream>>>(Wv, wtv, D, D);
  transpose_conv<<<dim3(32, 32), 256, 0, stream>>>(Wo, wto, D, D);
  transpose_conv<<<dim3(500, 32), 256, 0, stream>>>(Wlm, lmt, D, VOCAB);

  // q = noise_emb @ Wq ; k/v = kv @ Wk/Wv (v stored transposed: [feature][token])
  gemm128<EPI_PLAIN><<<dim3(8, 16, 1), 256, 0, stream>>>(kv + (long)L * D, D, 0, wtq, D, 0, qb, D, 0, D);
  gemm128<EPI_PLAIN><<<dim3(16, 16, 1), 256, 0, stream>>>(kv, D, 0, wtk, D, 0, kb, D, 0, D);
  gemm128<EPI_TRANS><<<dim3(16, 16, 1), 256, 0, stream>>>(kv, D, 0, wtv, D, 0, vt, D, 0, D);

  // scores[h] = mask(q_h @ k_h^T / sqrt(hd))
  gemm128<EPI_SCORES><<<dim3(8, 16, NH), 256, 0, stream>>>(qb, D, HD, kb, D, HD, sc, KV, (long)L * KV, HD);
  softmax_rows<<<NH * L, 256, 0, stream>>>(sc);
  // ctx[:, h*128:...] = attn_h @ v_h
  gemm128<EPI_PLAIN><<<dim3(8, 1, NH), 256, 0, stream>>>(sc, KV, (long)L * KV, vt, KV, (long)HD * KV, ctx, D, HD, KV);
  // hidden = ctx @ Wo ; logits = hidden @ lm_head
  gemm128<EPI_PLAIN><<<dim3(8, 16, 1), 256, 0, stream>>>(ctx, D, 0, wto, D, 0, hid, D, 0, D);
  gemm128<EPI_PLAIN><<<dim3(8, 250, 1), 256, 0, stream>>>(hid, D, 0, lmt, D, 0, lgt, VOCAB, 0, D);

  row_ce<<<1024, 256, 0, stream>>>(lgt, ids, rowbuf);
  final_reduce<<<1, 256, 0, stream>>>(rowbuf, lmask, out);
}

// Round 2
// 473.788 us; speedup vs baseline: 1.3789x; 1.3789x over previous
//
#include <hip/hip_runtime.h>

typedef unsigned int uint32;
typedef unsigned short u16;
typedef __attribute__((ext_vector_type(8))) short bf16x8;
typedef __attribute__((ext_vector_type(4))) float f32x4;

// ---------- helpers ----------
__device__ __forceinline__ u16 f2b(float f) {            // fp32 -> bf16 RNE
  uint32 u = __float_as_uint(f);
  u = (u + 0x7fffu + ((u >> 16) & 1u)) >> 16;
  return (u16)u;
}
__device__ __forceinline__ float b2f(u16 h) {
  return __uint_as_float(((uint32)h) << 16);
}
__device__ __forceinline__ void gl_lds16(const void* g, void* l) {
  typedef const __attribute__((address_space(1))) void* gp_t;
  typedef __attribute__((address_space(3))) void* lp_t;
  __builtin_amdgcn_global_load_lds((gp_t)g, (lp_t)l, 16, 0, 0);
}

// ---------- model constants ----------
#define L 1024
#define D 2048
#define NH 16
#define HD 128
#define VOCAB 32000
#define KV 2048
#define MASK_ID 31999

// ---------- ws layout (bytes) ----------
static constexpr long OFF_KV  = 0;                       // 2048*2048*2
static constexpr long OFF_WTQ = OFF_KV  + 8388608;
static constexpr long OFF_WTK = OFF_WTQ + 8388608;       // contiguous after WTQ (merged QKV GEMM relies on it)
static constexpr long OFF_WTV = OFF_WTK + 8388608;
static constexpr long OFF_WTO = OFF_WTV + 8388608;
static constexpr long OFF_Q   = OFF_WTO + 8388608;       // 1024*2048*2
static constexpr long OFF_K   = OFF_Q   + 4194304;       // 2048*2048*2
static constexpr long OFF_VT  = OFF_K   + 8388608;       // 2048*2048*2 (feature x token)
static constexpr long OFF_SC  = OFF_VT  + 8388608;       // 16*1024*2048*2
static constexpr long OFF_CTX = OFF_SC  + 67108864;      // 1024*2048*2
static constexpr long OFF_HID = OFF_CTX + 4194304;       // 1024*2048*2
static constexpr long OFF_LMT = OFF_HID + 4194304;       // 32000*2048*2
static constexpr long OFF_LOG = OFF_LMT + 131072000;     // 1024*32000*2
static constexpr long OFF_ROW = OFF_LOG + 65536000;      // 1024*2*4
static constexpr long WS_NEED = OFF_ROW + 8192;

// ---------- prep: build kv = [hidden_states ; noise_emb] in bf16 ----------
__global__ __launch_bounds__(256) void prep_kv(const float* __restrict__ hs,
                                               const int* __restrict__ ids,
                                               const float* __restrict__ emb,
                                               u16* __restrict__ kv) {
  int r = blockIdx.x;           // 0..2047
  int t = threadIdx.x;          // 256 threads * 8 elems
  const float* src;
  if (r < L) {
    src = hs + (long)r * D;
  } else {
    int p = r - L;
    int id = ((p & 15) == 0) ? ids[p] : MASK_ID;
    src = emb + (long)id * D;
  }
  float4 a = *(const float4*)(src + t * 8);
  float4 b = *(const float4*)(src + t * 8 + 4);
  u16* dst = kv + (long)r * D + t * 8;
  ushort4 o0, o1;
  o0.x = f2b(a.x); o0.y = f2b(a.y); o0.z = f2b(a.z); o0.w = f2b(a.w);
  o1.x = f2b(b.x); o1.y = f2b(b.y); o1.z = f2b(b.z); o1.w = f2b(b.w);
  *(ushort4*)dst = o0;
  *(ushort4*)(dst + 4) = o1;
}

// ---------- transpose + convert: W fp32 [K][N] -> WT bf16 [N][K] ----------
__device__ __forceinline__ void transpose_body(const float* __restrict__ W,
                                               u16* __restrict__ WT,
                                               int Kd, int Nd) {
  __shared__ float tile[64][65];
  int n0 = blockIdx.x * 64;
  int k0 = blockIdx.y * 64;
  int t = threadIdx.x;
#pragma unroll
  for (int p = 0; p < 4; ++p) {
    int idx = p * 256 + t;
    int r = idx >> 4;           // k local 0..63
    int c = (idx & 15) << 2;    // n local 0..60
    float4 v = *(const float4*)(W + (long)(k0 + r) * Nd + n0 + c);
    tile[r][c] = v.x; tile[r][c + 1] = v.y; tile[r][c + 2] = v.z; tile[r][c + 3] = v.w;
  }
  __syncthreads();
#pragma unroll
  for (int p = 0; p < 4; ++p) {
    int idx = p * 256 + t;
    int rn = idx >> 4;          // n local
    int ck = (idx & 15) << 2;   // k local
    ushort4 o;
    o.x = f2b(tile[ck][rn]);
    o.y = f2b(tile[ck + 1][rn]);
    o.z = f2b(tile[ck + 2][rn]);
    o.w = f2b(tile[ck + 3][rn]);
    *(ushort4*)(WT + (long)(n0 + rn) * Kd + k0 + ck) = o;
  }
}

__global__ __launch_bounds__(256) void transpose_conv(const float* __restrict__ W,
                                                      u16* __restrict__ WT,
                                                      int Kd, int Nd) {
  transpose_body(W, WT, Kd, Nd);
}

__global__ __launch_bounds__(256) void transpose4(const float* __restrict__ W0, const float* __restrict__ W1,
                                                  const float* __restrict__ W2, const float* __restrict__ W3,
                                                  u16* __restrict__ T0, u16* __restrict__ T1,
                                                  u16* __restrict__ T2, u16* __restrict__ T3) {
  int z = blockIdx.z;
  const float* W = (z == 0) ? W0 : (z == 1) ? W1 : (z == 2) ? W2 : W3;
  u16* T = (z == 0) ? T0 : (z == 1) ? T1 : (z == 2) ? T2 : T3;
  transpose_body(W, T, D, D);
}

// ---------- 128x128 MFMA GEMM, A [M][K] bf16 row-major, BT [N][K] bf16 row-major ----------
#define EPI_PLAIN 0
#define EPI_TRANS 1
#define EPI_SCORES 2
#define EPI_QKV 3

template <int EPI>
__global__ __launch_bounds__(256) void gemm128(const u16* __restrict__ A, int lda, long aHead,
                                               const u16* __restrict__ BT, int ldb, long bHead,
                                               u16* __restrict__ C, int ldc, long cHead,
                                               int Kd,
                                               u16* __restrict__ Cq, u16* __restrict__ Ck,
                                               u16* __restrict__ Cv) {
  if (EPI == EPI_QKV) {
    // Q output only uses A-rows >= 1024; blocks entirely in (rows<1024, Q cols) are dead.
    if (blockIdx.y < 16 && blockIdx.x < 8) return;
  }
  __shared__ __align__(16) char lds[16384];
  char* a_lds = lds;
  char* b_lds = lds + 8192;
  int tid = threadIdx.x;
  int lane = tid & 63;
  int wave = tid >> 6;
  int wr = wave >> 1, wc = wave & 1;
  int h = blockIdx.z;
  long tm = (long)blockIdx.x * 128;
  long tn = (long)blockIdx.y * 128;
  const u16* Ap = A + (long)h * aHead + tm * lda;
  const u16* Bp = BT + (long)h * bHead + tn * ldb;

  int soff = tid * 16;          // staging flat byte offset (4 KB per round)
  int srow = soff >> 6;         // 64 B per row (32 bf16)
  int scol = (soff & 63) >> 1;  // elem col within 32
  char* aldsb = a_lds + wave * 1024;  // wave-uniform LDS base
  char* bldsb = b_lds + wave * 1024;

  f32x4 acc[4][4];
#pragma unroll
  for (int i = 0; i < 4; ++i)
#pragma unroll
    for (int j = 0; j < 4; ++j) acc[i][j] = (f32x4){0.f, 0.f, 0.f, 0.f};

  for (int k0 = 0; k0 < Kd; k0 += 32) {
#pragma unroll
    for (int r = 0; r < 2; ++r) {
      gl_lds16(Ap + (long)(srow + r * 64) * lda + k0 + scol, aldsb + r * 4096);
      gl_lds16(Bp + (long)(srow + r * 64) * ldb + k0 + scol, bldsb + r * 4096);
    }
    __syncthreads();
    bf16x8 af[4], bfr[4];
    int ka = (lane >> 4) << 4;  // byte offset of this lane's 8 k-elems
#pragma unroll
    for (int mi = 0; mi < 4; ++mi)
      af[mi] = *(const bf16x8*)(a_lds + (wr * 64 + mi * 16 + (lane & 15)) * 64 + ka);
#pragma unroll
    for (int ni = 0; ni < 4; ++ni)
      bfr[ni] = *(const bf16x8*)(b_lds + (wc * 64 + ni * 16 + (lane & 15)) * 64 + ka);
#pragma unroll
    for (int mi = 0; mi < 4; ++mi)
#pragma unroll
      for (int ni = 0; ni < 4; ++ni)
        acc[mi][ni] = __builtin_amdgcn_mfma_f32_16x16x32_bf16(af[mi], bfr[ni], acc[mi][ni], 0, 0, 0);
    __syncthreads();
  }

  long crow0 = tm + wr * 64 + ((lane >> 4) << 2);
  int ccol0 = wc * 64 + (lane & 15);
  u16* Cp = C + (long)h * cHead;
  const float scale = 0.08838834764831845f;  // 1/sqrt(128)
#pragma unroll
  for (int mi = 0; mi < 4; ++mi) {
#pragma unroll
    for (int ni = 0; ni < 4; ++ni) {
      long col = tn + ccol0 + ni * 16;
#pragma unroll
      for (int j = 0; j < 4; ++j) {
        long row = crow0 + mi * 16 + j;
        float v = acc[mi][ni][j];
        if (EPI == EPI_PLAIN) {
          Cp[row * ldc + col] = f2b(v);
        } else if (EPI == EPI_TRANS) {
          Cp[col * ldc + row] = f2b(v);
        } else if (EPI == EPI_SCORES) {  // row = query token, col = key slot
          int rb = (int)row >> 4;
          int cb = (int)col >> 4;
          bool vis = (col < 1024) ? (cb < rb) : ((cb - 64) == rb);
          Cp[row * ldc + col] = f2b(vis ? v * scale : -1e30f);
        } else {  // EPI_QKV: col ranges [0,2048)=Q, [2048,4096)=K, [4096,6144)=V^T
          if (col < 2048) {
            if (row >= 1024) Cq[(row - 1024) * 2048 + col] = f2b(v);
          } else if (col < 4096) {
            Ck[row * 2048 + (col - 2048)] = f2b(v);
          } else {
            Cv[(col - 4096) * 2048 + row] = f2b(v);
          }
        }
      }
    }
  }
}

// ---------- 256x256 8-phase MFMA GEMM (T1+T2+T3+T4+T5), A [M][K], BT [N][K] ----------
// BK=64 K-tiles, split into K-halves of 32; LDS per buf: A_K0|A_K1|B_K0|B_K1, 16 KB each.
// Half-tile stage stream slot s: tile=s>>2, h=s&3 -> {0:B_K0, 1:A_K0, 2:B_K1, 3:A_K1}.
// Phase p of tile t stages slot 4t+6+p; vmcnt(6) at phases 4/8 (vmcnt(0) at final pair).
__global__ __launch_bounds__(512, 2) void gemm256(const u16* __restrict__ A, int lda,
                                                  const u16* __restrict__ BT, int ldb,
                                                  u16* __restrict__ C, int ldc,
                                                  int Kd, int mtiles) {
  __shared__ __align__(16) char lds[131072];
  int nwg = gridDim.x;
  int orig = blockIdx.x;
  // bijective XCD swizzle (m204)
  int q8 = nwg >> 3, r8 = nwg & 7;
  int xcd = orig & 7, idx = orig >> 3;
  int wg = (xcd < r8 ? xcd * (q8 + 1) : r8 * (q8 + 1) + (xcd - r8) * q8) + idx;
  int tm = wg % mtiles, tn = wg / mtiles;

  int tid = threadIdx.x, lane = tid & 63, w = tid >> 6;
  int wm = w >> 2, wn = w & 3;
  const u16* Ap = A + (long)tm * 256 * lda;
  const u16* Bp = BT + (long)tn * 256 * ldb;
  int NT = Kd >> 6;             // K-tiles of 64; must be even, >= 2
  int maxs = NT << 2;

  // stage one half-tile (16 KB = 512 thr x 2 x 16 B); XOR-swizzled global source,
  // linear LDS dest (rule 21: inverse-swizzle the source, swizzle the read).
  auto STAGE_SLOT = [&](int s) {
    if (s >= maxs) return;
    int tau = s >> 2, hh = s & 3;
    int kind = (hh & 1) ^ 1;    // 0 = A, 1 = B
    int ks = hh >> 1;
    const u16* src = kind ? Bp : Ap;
    int ld = kind ? ldb : lda;
    char* dst0 = lds + (tau & 1) * 65536 + kind * 32768 + ks * 16384;
    long kbase = (long)tau * 64 + ks * 32;
#pragma unroll
    for (int l = 0; l < 2; ++l) {
      int o = tid * 16 + l * 8192;
      int rr = o >> 6;                       // row 0..255
      int ch = (o >> 4) & 3;                 // physical 16-B chunk slot
      int clog = ch ^ ((rr >> 1) & 3);       // logical k-chunk (involution)
      gl_lds16(src + (long)rr * ld + kbase + clog * 8, dst0 + w * 1024 + l * 8192);
    }
  };
  auto LDA = [&](int tau, int ks, int mi) -> bf16x8 {
    int rr = wm * 128 + mi * 16 + (lane & 15);
    int qq = lane >> 4;
    return *(const bf16x8*)(lds + (tau & 1) * 65536 + ks * 16384 + rr * 64 +
                            ((qq ^ ((rr >> 1) & 3)) << 4));
  };
  auto LDB = [&](int tau, int ks, int ni) -> bf16x8 {
    int rr = wn * 64 + ni * 16 + (lane & 15);
    int qq = lane >> 4;
    return *(const bf16x8*)(lds + (tau & 1) * 65536 + 32768 + ks * 16384 + rr * 64 +
                            ((qq ^ ((rr >> 1) & 3)) << 4));
  };

  f32x4 acc[8][4];
#pragma unroll
  for (int i = 0; i < 8; ++i)
#pragma unroll
    for (int j = 0; j < 4; ++j) acc[i][j] = (f32x4){0.f, 0.f, 0.f, 0.f};

  // prologue: tile0 fully + 3 halves of tile1
  STAGE_SLOT(0); STAGE_SLOT(1); STAGE_SLOT(2); STAGE_SLOT(3);
  asm volatile("s_waitcnt vmcnt(4)" ::: "memory");
  STAGE_SLOT(4); STAGE_SLOT(5); STAGE_SLOT(6);
  asm volatile("s_waitcnt vmcnt(6)" ::: "memory");   // tile0 fully staged
  __builtin_amdgcn_s_barrier();
  __builtin_amdgcn_sched_barrier(0);

  bf16x8 bfr[4];

#define G256_PHASE(TAU, KS, MH, SLOT, WAITV)                                   \
  {                                                                            \
    bf16x8 af[4];                                                              \
    if (MH == 0) {                                                             \
      bfr[0] = LDB(TAU, KS, 0); bfr[1] = LDB(TAU, KS, 1);                      \
      bfr[2] = LDB(TAU, KS, 2); bfr[3] = LDB(TAU, KS, 3);                      \
    }                                                                          \
    af[0] = LDA(TAU, KS, MH * 4 + 0); af[1] = LDA(TAU, KS, MH * 4 + 1);        \
    af[2] = LDA(TAU, KS, MH * 4 + 2); af[3] = LDA(TAU, KS, MH * 4 + 3);        \
    STAGE_SLOT(SLOT);                                                          \
    __builtin_amdgcn_sched_barrier(0);                                         \
    __builtin_amdgcn_s_barrier();                                              \
    asm volatile("s_waitcnt lgkmcnt(0)" ::: "memory");                         \
    __builtin_amdgcn_sched_barrier(0);                                         \
    __builtin_amdgcn_s_setprio(1);                                             \
    _Pragma("unroll")                                                          \
    for (int mi2 = 0; mi2 < 4; ++mi2)                                          \
      _Pragma("unroll")                                                        \
      for (int ni = 0; ni < 4; ++ni)                                           \
        acc[MH * 4 + mi2][ni] = __builtin_amdgcn_mfma_f32_16x16x32_bf16(       \
            af[mi2], bfr[ni], acc[MH * 4 + mi2][ni], 0, 0, 0);                 \
    __builtin_amdgcn_s_setprio(0);                                             \
    __builtin_amdgcn_sched_barrier(0);                                         \
    if (WAITV == 6) asm volatile("s_waitcnt vmcnt(6)" ::: "memory");           \
    else if (WAITV == 0) asm volatile("s_waitcnt vmcnt(0)" ::: "memory");      \
    __builtin_amdgcn_s_barrier();                                              \
    __builtin_amdgcn_sched_barrier(0);                                         \
  }

  for (int t = 0; t < NT; t += 2) {
    int s0 = 4 * t;
    int w4 = (t + 2 >= NT) ? 0 : 6;     // final pair: drain so last tile is fully staged
    G256_PHASE(t,     0, 0, s0 + 7,  -1)
    G256_PHASE(t,     0, 1, s0 + 8,  -1)
    G256_PHASE(t,     1, 0, s0 + 9,  -1)
    G256_PHASE(t,     1, 1, s0 + 10, w4)
    G256_PHASE(t + 1, 0, 0, s0 + 11, -1)
    G256_PHASE(t + 1, 0, 1, s0 + 12, -1)
    G256_PHASE(t + 1, 1, 0, s0 + 13, -1)
    G256_PHASE(t + 1, 1, 1, s0 + 14, 6)
  }
#undef G256_PHASE

  long crow = (long)tm * 256 + wm * 128 + ((lane >> 4) << 2);
  long ccol = (long)tn * 256 + wn * 64 + (lane & 15);
#pragma unroll
  for (int mi = 0; mi < 8; ++mi)
#pragma unroll
    for (int ni = 0; ni < 4; ++ni)
#pragma unroll
      for (int j = 0; j < 4; ++j)
        C[(crow + mi * 16 + j) * ldc + ccol + ni * 16] = f2b(acc[mi][ni][j]);
}

// ---------- row softmax over 2048 (in place, bf16) ----------
__global__ __launch_bounds__(256) void softmax_rows(u16* __restrict__ sc) {
  long row = blockIdx.x;  // 16*1024 rows
  u16* p = sc + row * 2048;
  int t = threadIdx.x;
  bf16x8 v = *(const bf16x8*)(p + t * 8);
  float f[8];
#pragma unroll
  for (int i = 0; i < 8; ++i) f[i] = b2f((u16)v[i]);
  float m = f[0];
#pragma unroll
  for (int i = 1; i < 8; ++i) m = fmaxf(m, f[i]);
  for (int off = 1; off < 64; off <<= 1) m = fmaxf(m, __shfl_xor(m, off));
  __shared__ float redm[4], reds[4];
  if ((t & 63) == 0) redm[t >> 6] = m;
  __syncthreads();
  m = fmaxf(fmaxf(redm[0], redm[1]), fmaxf(redm[2], redm[3]));
  float e[8];
  float s = 0.f;
#pragma unroll
  for (int i = 0; i < 8; ++i) { e[i] = __expf(f[i] - m); s += e[i]; }
  for (int off = 1; off < 64; off <<= 1) s += __shfl_xor(s, off);
  if ((t & 63) == 0) reds[t >> 6] = s;
  __syncthreads();
  s = reds[0] + reds[1] + reds[2] + reds[3];
  float inv = 1.f / s;
  bf16x8 o;
#pragma unroll
  for (int i = 0; i < 8; ++i) o[i] = (short)f2b(e[i] * inv);
  *(bf16x8*)(p + t * 8) = o;
}

// ---------- per-row CE + argmax over vocab ----------
__global__ __launch_bounds__(256) void row_ce(const u16* __restrict__ logits,
                                              const int* __restrict__ ids,
                                              float* __restrict__ rowbuf) {
  int row = blockIdx.x;
  const u16* p = logits + (long)row * VOCAB;
  int t = threadIdx.x;
  int lane = t & 63, w = t >> 6;
  float m = -1e30f;
  int am = VOCAB;
  for (int i = t * 8; i < VOCAB; i += 2048) {
    bf16x8 v = *(const bf16x8*)(p + i);
#pragma unroll
    for (int j = 0; j < 8; ++j) {
      float f = b2f((u16)v[j]);
      if (f > m) { m = f; am = i + j; }
      else if (f == m && (i + j) < am) am = i + j;
    }
  }
  for (int off = 1; off < 64; off <<= 1) {
    float om = __shfl_xor(m, off);
    int oa = __shfl_xor(am, off);
    if (om > m || (om == m && oa < am)) { m = om; am = oa; }
  }
  __shared__ float smax[4]; __shared__ int sidx[4]; __shared__ float ssum[4];
  if (lane == 0) { smax[w] = m; sidx[w] = am; }
  __syncthreads();
  float gm = smax[0]; int gi = sidx[0];
#pragma unroll
  for (int q = 1; q < 4; ++q) {
    if (smax[q] > gm || (smax[q] == gm && sidx[q] < gi)) { gm = smax[q]; gi = sidx[q]; }
  }
  float s = 0.f;
  for (int i = t * 8; i < VOCAB; i += 2048) {
    bf16x8 v = *(const bf16x8*)(p + i);
#pragma unroll
    for (int j = 0; j < 8; ++j) s += __expf(b2f((u16)v[j]) - gm);
  }
  for (int off = 1; off < 64; off <<= 1) s += __shfl_xor(s, off);
  if (lane == 0) ssum[w] = s;
  __syncthreads();
  if (t == 0) {
    float gs = ssum[0] + ssum[1] + ssum[2] + ssum[3];
    int tgt = ids[row];
    float tl = b2f(p[tgt]);
    rowbuf[row * 2] = gm + logf(gs) - tl;          // CE
    rowbuf[row * 2 + 1] = (gi == tgt) ? 1.f : 0.f; // correct
  }
}

// ---------- final: masked mean loss + accuracy ----------
__global__ __launch_bounds__(256) void final_reduce(const float* __restrict__ rowbuf,
                                                    const float* __restrict__ loss_mask,
                                                    float* __restrict__ out) {
  int t = threadIdx.x;
  float ce = 0.f, cnt = 0.f, cor = 0.f;
  for (int r = t; r < L; r += 256) {
    bool valid = (r >= 16) && ((r & 15) != 0);
    float comb = loss_mask[r] * (valid ? 1.f : 0.f);
    if (comb > 1e-6f) {
      ce += rowbuf[r * 2];
      cor += rowbuf[r * 2 + 1];
      cnt += 1.f;
    }
  }
  for (int off = 1; off < 64; off <<= 1) {
    ce += __shfl_xor(ce, off);
    cnt += __shfl_xor(cnt, off);
    cor += __shfl_xor(cor, off);
  }
  __shared__ float s1[4], s2[4], s3[4];
  int lane = t & 63, w = t >> 6;
  if (lane == 0) { s1[w] = ce; s2[w] = cnt; s3[w] = cor; }
  __syncthreads();
  if (t == 0) {
    float C = s1[0] + s1[1] + s1[2] + s1[3];
    float N = s2[0] + s2[1] + s2[2] + s2[3];
    float R = s3[0] + s3[1] + s3[2] + s3[3];
    out[0] = C / N;
    out[1] = R / N;
  }
}

__global__ void ws_too_small(float* out, float mb) {
  if (threadIdx.x == 0) { out[0] = 1e6f + mb; out[1] = -1e6f; }
}

// ---------- launch ----------
extern "C" void kernel_launch(void* const* d_in, const int* in_sizes, int n_in,
                              void* d_out, int out_size, void* d_ws, size_t ws_size,
                              hipStream_t stream) {
  const int* ids = (const int*)d_in[0];
  const float* hs = (const float*)d_in[2];
  const float* lmask = (const float*)d_in[3];
  const float* emb = (const float*)d_in[4];
  const float* Wq = (const float*)d_in[5];
  const float* Wk = (const float*)d_in[6];
  const float* Wv = (const float*)d_in[7];
  const float* Wo = (const float*)d_in[8];
  const float* Wlm = (const float*)d_in[9];
  float* out = (float*)d_out;
  char* ws = (char*)d_ws;

  if (ws_size < (size_t)WS_NEED) {
    ws_too_small<<<1, 64, 0, stream>>>(out, (float)(ws_size >> 20));
    return;
  }

  u16* kv  = (u16*)(ws + OFF_KV);
  u16* wtq = (u16*)(ws + OFF_WTQ);
  u16* wtk = (u16*)(ws + OFF_WTK);
  u16* wtv = (u16*)(ws + OFF_WTV);
  u16* wto = (u16*)(ws + OFF_WTO);
  u16* qb  = (u16*)(ws + OFF_Q);
  u16* kb  = (u16*)(ws + OFF_K);
  u16* vt  = (u16*)(ws + OFF_VT);
  u16* sc  = (u16*)(ws + OFF_SC);
  u16* ctx = (u16*)(ws + OFF_CTX);
  u16* hid = (u16*)(ws + OFF_HID);
  u16* lmt = (u16*)(ws + OFF_LMT);
  u16* lgt = (u16*)(ws + OFF_LOG);
  float* rowbuf = (float*)(ws + OFF_ROW);

  prep_kv<<<2048, 256, 0, stream>>>(hs, ids, emb, kv);
  transpose4<<<dim3(32, 32, 4), 256, 0, stream>>>(Wq, Wk, Wv, Wo, wtq, wtk, wtv, wto);
  transpose_conv<<<dim3(500, 32), 256, 0, stream>>>(Wlm, lmt, D, VOCAB);

  // fused q/k/v projection: B = [wtq | wtk | wtv] (contiguous), per-range epilogue
  gemm128<EPI_QKV><<<dim3(16, 48, 1), 256, 0, stream>>>(kv, D, 0, wtq, D, 0,
                                                        nullptr, 0, 0, D, qb, kb, vt);

  // scores[h] = mask(q_h @ k_h^T / sqrt(hd))
  gemm128<EPI_SCORES><<<dim3(8, 16, NH), 256, 0, stream>>>(qb, D, HD, kb, D, HD, sc, KV,
                                                           (long)L * KV, HD,
                                                           nullptr, nullptr, nullptr);
  softmax_rows<<<NH * L, 256, 0, stream>>>(sc);
  // ctx[:, h*128:...] = attn_h @ v_h
  gemm128<EPI_PLAIN><<<dim3(8, 1, NH), 256, 0, stream>>>(sc, KV, (long)L * KV, vt, KV,
                                                         (long)HD * KV, ctx, D, HD, KV,
                                                         nullptr, nullptr, nullptr);
  // hidden = ctx @ Wo
  gemm128<EPI_PLAIN><<<dim3(8, 16, 1), 256, 0, stream>>>(ctx, D, 0, wto, D, 0, hid, D, 0, D,
                                                         nullptr, nullptr, nullptr);
  // logits = hidden @ lm_head  (256^2 8-phase kernel; grid 4 x 125 = 500)
  gemm256<<<dim3(500), 512, 0, stream>>>(hid, D, lmt, D, lgt, VOCAB, D, 4);

  row_ce<<<1024, 256, 0, stream>>>(lgt, ids, rowbuf);
  final_reduce<<<1, 256, 0, stream>>>(rowbuf, lmask, out);
}

// Round 3
// 458.502 us; speedup vs baseline: 1.4249x; 1.0333x over previous
//
#include <hip/hip_runtime.h>

typedef unsigned int uint32;
typedef unsigned short u16;
typedef __attribute__((ext_vector_type(8))) short bf16x8;
typedef __attribute__((ext_vector_type(4))) float f32x4;

// ---------- helpers ----------
__device__ __forceinline__ u16 f2b(float f) {            // fp32 -> bf16 RNE
  uint32 u = __float_as_uint(f);
  u = (u + 0x7fffu + ((u >> 16) & 1u)) >> 16;
  return (u16)u;
}
__device__ __forceinline__ float b2f(u16 h) {
  return __uint_as_float(((uint32)h) << 16);
}
__device__ __forceinline__ void gl_lds16(const void* g, void* l) {
  typedef const __attribute__((address_space(1))) void* gp_t;
  typedef __attribute__((address_space(3))) void* lp_t;
  __builtin_amdgcn_global_load_lds((gp_t)g, (lp_t)l, 16, 0, 0);
}

// ---------- model constants ----------
#define L 1024
#define D 2048
#define NH 16
#define HD 128
#define VOCAB 32000
#define KV 2048
#define MASK_ID 31999

// ---------- ws layout (bytes) ----------
static constexpr long OFF_KV  = 0;                       // 2048*2048*2
static constexpr long OFF_WTQ = OFF_KV  + 8388608;
static constexpr long OFF_WTK = OFF_WTQ + 8388608;       // contiguous after WTQ (merged QKV GEMM relies on it)
static constexpr long OFF_WTV = OFF_WTK + 8388608;
static constexpr long OFF_WTO = OFF_WTV + 8388608;
static constexpr long OFF_Q   = OFF_WTO + 8388608;       // 1024*2048*2
static constexpr long OFF_K   = OFF_Q   + 4194304;       // 2048*2048*2
static constexpr long OFF_VT  = OFF_K   + 8388608;       // 2048*2048*2 (feature x token)
static constexpr long OFF_SC  = OFF_VT  + 8388608;       // (unused now, kept for layout stability)
static constexpr long OFF_CTX = OFF_SC  + 67108864;      // 1024*2048*2
static constexpr long OFF_HID = OFF_CTX + 4194304;       // 1024*2048*2
static constexpr long OFF_LMT = OFF_HID + 4194304;       // 32000*2048*2
static constexpr long OFF_LOG = OFF_LMT + 131072000;     // 1024*32000*2
static constexpr long OFF_ROW = OFF_LOG + 65536000;      // 1024*2*4
static constexpr long WS_NEED = OFF_ROW + 8192;

// ---------- prep: build kv = [hidden_states ; noise_emb] in bf16 ----------
__global__ __launch_bounds__(256) void prep_kv(const float* __restrict__ hs,
                                               const int* __restrict__ ids,
                                               const float* __restrict__ emb,
                                               u16* __restrict__ kv) {
  int r = blockIdx.x;           // 0..2047
  int t = threadIdx.x;          // 256 threads * 8 elems
  const float* src;
  if (r < L) {
    src = hs + (long)r * D;
  } else {
    int p = r - L;
    int id = ((p & 15) == 0) ? ids[p] : MASK_ID;
    src = emb + (long)id * D;
  }
  float4 a = *(const float4*)(src + t * 8);
  float4 b = *(const float4*)(src + t * 8 + 4);
  u16* dst = kv + (long)r * D + t * 8;
  ushort4 o0, o1;
  o0.x = f2b(a.x); o0.y = f2b(a.y); o0.z = f2b(a.z); o0.w = f2b(a.w);
  o1.x = f2b(b.x); o1.y = f2b(b.y); o1.z = f2b(b.z); o1.w = f2b(b.w);
  *(ushort4*)dst = o0;
  *(ushort4*)(dst + 4) = o1;
}

// ---------- transpose + convert: W fp32 [K][N] -> WT bf16 [N][K] ----------
__device__ __forceinline__ void transpose_body(const float* __restrict__ W,
                                               u16* __restrict__ WT,
                                               int Kd, int Nd) {
  __shared__ float tile[64][65];
  int n0 = blockIdx.x * 64;
  int k0 = blockIdx.y * 64;
  int t = threadIdx.x;
#pragma unroll
  for (int p = 0; p < 4; ++p) {
    int idx = p * 256 + t;
    int r = idx >> 4;           // k local 0..63
    int c = (idx & 15) << 2;    // n local 0..60
    float4 v = *(const float4*)(W + (long)(k0 + r) * Nd + n0 + c);
    tile[r][c] = v.x; tile[r][c + 1] = v.y; tile[r][c + 2] = v.z; tile[r][c + 3] = v.w;
  }
  __syncthreads();
#pragma unroll
  for (int p = 0; p < 4; ++p) {
    int idx = p * 256 + t;
    int rn = idx >> 4;          // n local
    int ck = (idx & 15) << 2;   // k local
    ushort4 o;
    o.x = f2b(tile[ck][rn]);
    o.y = f2b(tile[ck + 1][rn]);
    o.z = f2b(tile[ck + 2][rn]);
    o.w = f2b(tile[ck + 3][rn]);
    *(ushort4*)(WT + (long)(n0 + rn) * Kd + k0 + ck) = o;
  }
}

__global__ __launch_bounds__(256) void transpose_conv(const float* __restrict__ W,
                                                      u16* __restrict__ WT,
                                                      int Kd, int Nd) {
  transpose_body(W, WT, Kd, Nd);
}

__global__ __launch_bounds__(256) void transpose4(const float* __restrict__ W0, const float* __restrict__ W1,
                                                  const float* __restrict__ W2, const float* __restrict__ W3,
                                                  u16* __restrict__ T0, u16* __restrict__ T1,
                                                  u16* __restrict__ T2, u16* __restrict__ T3) {
  int z = blockIdx.z;
  const float* W = (z == 0) ? W0 : (z == 1) ? W1 : (z == 2) ? W2 : W3;
  u16* T = (z == 0) ? T0 : (z == 1) ? T1 : (z == 2) ? T2 : T3;
  transpose_body(W, T, D, D);
}

// ---------- 128x128 MFMA GEMM (2-phase), A [M][K] bf16, BT [N][K] bf16 ----------
#define EPI_PLAIN 0
#define EPI_QKV 3

template <int EPI>
__global__ __launch_bounds__(256) void gemm128(const u16* __restrict__ A, int lda, long aHead,
                                               const u16* __restrict__ BT, int ldb, long bHead,
                                               u16* __restrict__ C, int ldc, long cHead,
                                               int Kd) {
  __shared__ __align__(16) char lds[16384];
  char* a_lds = lds;
  char* b_lds = lds + 8192;
  int tid = threadIdx.x;
  int lane = tid & 63;
  int wave = tid >> 6;
  int wr = wave >> 1, wc = wave & 1;
  int h = blockIdx.z;
  long tm = (long)blockIdx.x * 128;
  long tn = (long)blockIdx.y * 128;
  const u16* Ap = A + (long)h * aHead + tm * lda;
  const u16* Bp = BT + (long)h * bHead + tn * ldb;

  int soff = tid * 16;
  int srow = soff >> 6;
  int scol = (soff & 63) >> 1;
  char* aldsb = a_lds + wave * 1024;
  char* bldsb = b_lds + wave * 1024;

  f32x4 acc[4][4];
#pragma unroll
  for (int i = 0; i < 4; ++i)
#pragma unroll
    for (int j = 0; j < 4; ++j) acc[i][j] = (f32x4){0.f, 0.f, 0.f, 0.f};

  for (int k0 = 0; k0 < Kd; k0 += 32) {
#pragma unroll
    for (int r = 0; r < 2; ++r) {
      gl_lds16(Ap + (long)(srow + r * 64) * lda + k0 + scol, aldsb + r * 4096);
      gl_lds16(Bp + (long)(srow + r * 64) * ldb + k0 + scol, bldsb + r * 4096);
    }
    __syncthreads();
    bf16x8 af[4], bfr[4];
    int ka = (lane >> 4) << 4;
#pragma unroll
    for (int mi = 0; mi < 4; ++mi)
      af[mi] = *(const bf16x8*)(a_lds + (wr * 64 + mi * 16 + (lane & 15)) * 64 + ka);
#pragma unroll
    for (int ni = 0; ni < 4; ++ni)
      bfr[ni] = *(const bf16x8*)(b_lds + (wc * 64 + ni * 16 + (lane & 15)) * 64 + ka);
#pragma unroll
    for (int mi = 0; mi < 4; ++mi)
#pragma unroll
      for (int ni = 0; ni < 4; ++ni)
        acc[mi][ni] = __builtin_amdgcn_mfma_f32_16x16x32_bf16(af[mi], bfr[ni], acc[mi][ni], 0, 0, 0);
    __syncthreads();
  }

  long crow0 = tm + wr * 64 + ((lane >> 4) << 2);
  int ccol0 = wc * 64 + (lane & 15);
  u16* Cp = C + (long)h * cHead;
#pragma unroll
  for (int mi = 0; mi < 4; ++mi) {
#pragma unroll
    for (int ni = 0; ni < 4; ++ni) {
      long col = tn + ccol0 + ni * 16;
#pragma unroll
      for (int j = 0; j < 4; ++j) {
        long row = crow0 + mi * 16 + j;
        Cp[row * ldc + col] = f2b(acc[mi][ni][j]);
      }
    }
  }
}

// ---------- 256x256 8-phase MFMA GEMM (T1+T2+T3+T4+T5), A [M][K], BT [N][K] ----------
// EPI_PLAIN: C[row][col]. EPI_QKV: BT = [Wq^T|Wk^T|Wv^T] (N=6144); routes to qb/kb/vt,
// grid = 160 live tiles (dead Q tiles tm<4,tn<8 skipped).
template <int EPI>
__global__ __launch_bounds__(512, 2) void gemm256(const u16* __restrict__ A, int lda,
                                                  const u16* __restrict__ BT, int ldb,
                                                  u16* __restrict__ C, int ldc,
                                                  int Kd, int mtiles,
                                                  u16* __restrict__ Cq, u16* __restrict__ Ck,
                                                  u16* __restrict__ Cv) {
  __shared__ __align__(16) char lds[131072];
  int nwg = gridDim.x;
  int orig = blockIdx.x;
  // bijective XCD swizzle (m204)
  int q8 = nwg >> 3, r8 = nwg & 7;
  int xcd = orig & 7, idx = orig >> 3;
  int wg = (xcd < r8 ? xcd * (q8 + 1) : r8 * (q8 + 1) + (xcd - r8) * q8) + idx;
  int tm, tn;
  if (EPI == EPI_QKV) {
    if (wg < 32) { tn = wg >> 2; tm = 4 + (wg & 3); }
    else { int e = wg - 32; tn = 8 + (e >> 3); tm = e & 7; }
  } else {
    tm = wg % mtiles; tn = wg / mtiles;
  }

  int tid = threadIdx.x, lane = tid & 63, w = tid >> 6;
  int wm = w >> 2, wn = w & 3;
  const u16* Ap = A + (long)tm * 256 * lda;
  const u16* Bp = BT + (long)tn * 256 * ldb;
  int NT = Kd >> 6;             // K-tiles of 64; must be even, >= 2
  int maxs = NT << 2;

  auto STAGE_SLOT = [&](int s) {
    if (s >= maxs) return;
    int tau = s >> 2, hh = s & 3;
    int kind = (hh & 1) ^ 1;    // 0 = A, 1 = B
    int ks = hh >> 1;
    const u16* src = kind ? Bp : Ap;
    int ld = kind ? ldb : lda;
    char* dst0 = lds + (tau & 1) * 65536 + kind * 32768 + ks * 16384;
    long kbase = (long)tau * 64 + ks * 32;
#pragma unroll
    for (int l = 0; l < 2; ++l) {
      int o = tid * 16 + l * 8192;
      int rr = o >> 6;
      int ch = (o >> 4) & 3;
      int clog = ch ^ ((rr >> 1) & 3);
      gl_lds16(src + (long)rr * ld + kbase + clog * 8, dst0 + w * 1024 + l * 8192);
    }
  };
  auto LDA = [&](int tau, int ks, int mi) -> bf16x8 {
    int rr = wm * 128 + mi * 16 + (lane & 15);
    int qq = lane >> 4;
    return *(const bf16x8*)(lds + (tau & 1) * 65536 + ks * 16384 + rr * 64 +
                            ((qq ^ ((rr >> 1) & 3)) << 4));
  };
  auto LDB = [&](int tau, int ks, int ni) -> bf16x8 {
    int rr = wn * 64 + ni * 16 + (lane & 15);
    int qq = lane >> 4;
    return *(const bf16x8*)(lds + (tau & 1) * 65536 + 32768 + ks * 16384 + rr * 64 +
                            ((qq ^ ((rr >> 1) & 3)) << 4));
  };

  f32x4 acc[8][4];
#pragma unroll
  for (int i = 0; i < 8; ++i)
#pragma unroll
    for (int j = 0; j < 4; ++j) acc[i][j] = (f32x4){0.f, 0.f, 0.f, 0.f};

  STAGE_SLOT(0); STAGE_SLOT(1); STAGE_SLOT(2); STAGE_SLOT(3);
  asm volatile("s_waitcnt vmcnt(4)" ::: "memory");
  STAGE_SLOT(4); STAGE_SLOT(5); STAGE_SLOT(6);
  asm volatile("s_waitcnt vmcnt(6)" ::: "memory");
  __builtin_amdgcn_s_barrier();
  __builtin_amdgcn_sched_barrier(0);

  bf16x8 bfr[4];

#define G256_PHASE(TAU, KS, MH, SLOT, WAITV)                                   \
  {                                                                            \
    bf16x8 af[4];                                                              \
    if (MH == 0) {                                                             \
      bfr[0] = LDB(TAU, KS, 0); bfr[1] = LDB(TAU, KS, 1);                      \
      bfr[2] = LDB(TAU, KS, 2); bfr[3] = LDB(TAU, KS, 3);                      \
    }                                                                          \
    af[0] = LDA(TAU, KS, MH * 4 + 0); af[1] = LDA(TAU, KS, MH * 4 + 1);        \
    af[2] = LDA(TAU, KS, MH * 4 + 2); af[3] = LDA(TAU, KS, MH * 4 + 3);        \
    STAGE_SLOT(SLOT);                                                          \
    __builtin_amdgcn_sched_barrier(0);                                         \
    __builtin_amdgcn_s_barrier();                                              \
    asm volatile("s_waitcnt lgkmcnt(0)" ::: "memory");                         \
    __builtin_amdgcn_sched_barrier(0);                                         \
    __builtin_amdgcn_s_setprio(1);                                             \
    _Pragma("unroll")                                                          \
    for (int mi2 = 0; mi2 < 4; ++mi2)                                          \
      _Pragma("unroll")                                                        \
      for (int ni = 0; ni < 4; ++ni)                                           \
        acc[MH * 4 + mi2][ni] = __builtin_amdgcn_mfma_f32_16x16x32_bf16(       \
            af[mi2], bfr[ni], acc[MH * 4 + mi2][ni], 0, 0, 0);                 \
    __builtin_amdgcn_s_setprio(0);                                             \
    __builtin_amdgcn_sched_barrier(0);                                         \
    if (WAITV == 6) asm volatile("s_waitcnt vmcnt(6)" ::: "memory");           \
    else if (WAITV == 0) asm volatile("s_waitcnt vmcnt(0)" ::: "memory");      \
    __builtin_amdgcn_s_barrier();                                              \
    __builtin_amdgcn_sched_barrier(0);                                         \
  }

  for (int t = 0; t < NT; t += 2) {
    int s0 = 4 * t;
    int w4 = (t + 2 >= NT) ? 0 : 6;
    G256_PHASE(t,     0, 0, s0 + 7,  -1)
    G256_PHASE(t,     0, 1, s0 + 8,  -1)
    G256_PHASE(t,     1, 0, s0 + 9,  -1)
    G256_PHASE(t,     1, 1, s0 + 10, w4)
    G256_PHASE(t + 1, 0, 0, s0 + 11, -1)
    G256_PHASE(t + 1, 0, 1, s0 + 12, -1)
    G256_PHASE(t + 1, 1, 0, s0 + 13, -1)
    G256_PHASE(t + 1, 1, 1, s0 + 14, 6)
  }
#undef G256_PHASE

  long crow = (long)tm * 256 + wm * 128 + ((lane >> 4) << 2);
  long ccol = (long)tn * 256 + wn * 64 + (lane & 15);
#pragma unroll
  for (int mi = 0; mi < 8; ++mi)
#pragma unroll
    for (int ni = 0; ni < 4; ++ni)
#pragma unroll
      for (int j = 0; j < 4; ++j) {
        long row = crow + mi * 16 + j;
        long col = ccol + ni * 16;
        u16 val = f2b(acc[mi][ni][j]);
        if (EPI == EPI_PLAIN) {
          C[row * ldc + col] = val;
        } else {
          if (col < 2048) {
            if (row >= 1024) Cq[(row - 1024) * D + col] = val;
          } else if (col < 4096) {
            Ck[row * D + (col - 2048)] = val;
          } else {
            Cv[(col - 4096) * KV + row] = val;
          }
        }
      }
}

// ---------- fused flash attention ----------
// One wave per (head, q-block of 16 rows). Visible keys: ctx blocks 0..rb-1 + noise block rb.
// S^T = mfma(K,Q) -> lane holds P[q=lane&15][keys (lane>>4)*4+j]; online softmax in that
// layout; O^T = mfma(V^T, P) keeps stats lane-local and gives 8-B contiguous ctx stores.
__global__ __launch_bounds__(256) void flash_attn(const u16* __restrict__ qb,
                                                  const u16* __restrict__ kb,
                                                  const u16* __restrict__ vt,
                                                  u16* __restrict__ ctx) {
  int tid = threadIdx.x;
  int lane = tid & 63;
  int wid = blockIdx.x * 4 + (tid >> 6);   // 0..1023
  int h = wid >> 6;
  int rb = wid & 63;
  int lq = lane & 15;
  int g = lane >> 4;
  const float scale = 0.08838834764831845f;  // 1/sqrt(128)

  // Q fragment (B-operand): lane holds Q[q=lq][d = c*32 + g*8 .. +8]
  const u16* qrow = qb + (long)(rb * 16 + lq) * D + h * HD + g * 8;
  bf16x8 qf[4];
#pragma unroll
  for (int c = 0; c < 4; ++c) qf[c] = *(const bf16x8*)(qrow + c * 32);

  f32x4 o[8];
#pragma unroll
  for (int i = 0; i < 8; ++i) o[i] = (f32x4){0.f, 0.f, 0.f, 0.f};
  float m = -1e30f, lsum = 0.f;

  int nb = rb + 1;
  for (int bp = 0; bp < nb; bp += 2) {
    bool validB = (bp + 1) < nb;
    int tokA = (bp < rb) ? bp * 16 : 1024 + rb * 16;
    int bB = bp + 1;
    int tokB = validB ? ((bB < rb) ? bB * 16 : 1024 + rb * 16) : tokA;

    // S^T fragments (keys local 0..15 in A-half, 16..31 in B-half)
    f32x4 sA = (f32x4){0.f, 0.f, 0.f, 0.f};
    f32x4 sB = (f32x4){0.f, 0.f, 0.f, 0.f};
    const u16* ka = kb + (long)(tokA + lq) * D + h * HD + g * 8;
#pragma unroll
    for (int c = 0; c < 4; ++c) {
      bf16x8 kf = *(const bf16x8*)(ka + c * 32);
      sA = __builtin_amdgcn_mfma_f32_16x16x32_bf16(kf, qf[c], sA, 0, 0, 0);
    }
    if (validB) {
      const u16* kbp = kb + (long)(tokB + lq) * D + h * HD + g * 8;
#pragma unroll
      for (int c = 0; c < 4; ++c) {
        bf16x8 kf = *(const bf16x8*)(kbp + c * 32);
        sB = __builtin_amdgcn_mfma_f32_16x16x32_bf16(kf, qf[c], sB, 0, 0, 0);
      }
    }

    float s8[8];
#pragma unroll
    for (int j = 0; j < 4; ++j) s8[j] = sA[j] * scale;
#pragma unroll
    for (int j = 0; j < 4; ++j) s8[4 + j] = validB ? sB[j] * scale : -1e30f;
    float mx = s8[0];
#pragma unroll
    for (int j = 1; j < 8; ++j) mx = fmaxf(mx, s8[j]);
    mx = fmaxf(mx, __shfl_xor(mx, 16));
    mx = fmaxf(mx, __shfl_xor(mx, 32));
    float mn = fmaxf(m, mx);
    float sc_f = __expf(m - mn);
    m = mn;
    float p[8], ps = 0.f;
#pragma unroll
    for (int j = 0; j < 8; ++j) { p[j] = __expf(s8[j] - mn); ps += p[j]; }
    ps += __shfl_xor(ps, 16);
    ps += __shfl_xor(ps, 32);
    lsum = lsum * sc_f + ps;

    // pack P to bf16 words: Aw0 = keys g*4+{0,1}, Aw1 = +{2,3} (local); same for B-half
    uint32 Aw0 = (uint32)f2b(p[0]) | ((uint32)f2b(p[1]) << 16);
    uint32 Aw1 = (uint32)f2b(p[2]) | ((uint32)f2b(p[3]) << 16);
    uint32 Bw0 = (uint32)f2b(p[4]) | ((uint32)f2b(p[5]) << 16);
    uint32 Bw1 = (uint32)f2b(p[6]) | ((uint32)f2b(p[7]) << 16);
    // PV B-frag: lane (g,lq) needs P[q=lq][local keys g*8..g*8+7]
    int s0 = (((2 * g) & 3) << 4) + lq;
    int s1 = (((2 * g + 1) & 3) << 4) + lq;
    uint32 a00 = (uint32)__shfl((int)Aw0, s0), a01 = (uint32)__shfl((int)Aw1, s0);
    uint32 a10 = (uint32)__shfl((int)Aw0, s1), a11 = (uint32)__shfl((int)Aw1, s1);
    uint32 b00 = (uint32)__shfl((int)Bw0, s0), b01 = (uint32)__shfl((int)Bw1, s0);
    uint32 b10 = (uint32)__shfl((int)Bw0, s1), b11 = (uint32)__shfl((int)Bw1, s1);
    union { uint32 u[4]; bf16x8 v; } pu;
    pu.u[0] = (g < 2) ? a00 : b00;
    pu.u[1] = (g < 2) ? a01 : b01;
    pu.u[2] = (g < 2) ? a10 : b10;
    pu.u[3] = (g < 2) ? a11 : b11;

    // O^T rescale (stats already in O^T's q=lane&15 layout) + PV
#pragma unroll
    for (int nt = 0; nt < 8; ++nt)
#pragma unroll
      for (int j = 0; j < 4; ++j) o[nt][j] *= sc_f;
    int tok_g = (g < 2) ? (tokA + g * 8) : (tokB + (g - 2) * 8);
    const u16* vrow = vt + (long)(h * HD + lq) * KV + tok_g;
#pragma unroll
    for (int nt = 0; nt < 8; ++nt) {
      bf16x8 vf = *(const bf16x8*)(vrow + (long)nt * 16 * KV);
      o[nt] = __builtin_amdgcn_mfma_f32_16x16x32_bf16(vf, pu.v, o[nt], 0, 0, 0);
    }
  }

  float inv = 1.f / lsum;
  u16* cp = ctx + (long)(rb * 16 + lq) * D + h * HD + g * 4;
#pragma unroll
  for (int nt = 0; nt < 8; ++nt) {
    ushort4 st;
    st.x = f2b(o[nt][0] * inv); st.y = f2b(o[nt][1] * inv);
    st.z = f2b(o[nt][2] * inv); st.w = f2b(o[nt][3] * inv);
    *(ushort4*)(cp + nt * 16) = st;
  }
}

// ---------- per-row CE + argmax over vocab ----------
__global__ __launch_bounds__(256) void row_ce(const u16* __restrict__ logits,
                                              const int* __restrict__ ids,
                                              float* __restrict__ rowbuf) {
  int row = blockIdx.x;
  const u16* p = logits + (long)row * VOCAB;
  int t = threadIdx.x;
  int lane = t & 63, w = t >> 6;
  float m = -1e30f;
  int am = VOCAB;
  for (int i = t * 8; i < VOCAB; i += 2048) {
    bf16x8 v = *(const bf16x8*)(p + i);
#pragma unroll
    for (int j = 0; j < 8; ++j) {
      float f = b2f((u16)v[j]);
      if (f > m) { m = f; am = i + j; }
      else if (f == m && (i + j) < am) am = i + j;
    }
  }
  for (int off = 1; off < 64; off <<= 1) {
    float om = __shfl_xor(m, off);
    int oa = __shfl_xor(am, off);
    if (om > m || (om == m && oa < am)) { m = om; am = oa; }
  }
  __shared__ float smax[4]; __shared__ int sidx[4]; __shared__ float ssum[4];
  if (lane == 0) { smax[w] = m; sidx[w] = am; }
  __syncthreads();
  float gm = smax[0]; int gi = sidx[0];
#pragma unroll
  for (int q = 1; q < 4; ++q) {
    if (smax[q] > gm || (smax[q] == gm && sidx[q] < gi)) { gm = smax[q]; gi = sidx[q]; }
  }
  float s = 0.f;
  for (int i = t * 8; i < VOCAB; i += 2048) {
    bf16x8 v = *(const bf16x8*)(p + i);
#pragma unroll
    for (int j = 0; j < 8; ++j) s += __expf(b2f((u16)v[j]) - gm);
  }
  for (int off = 1; off < 64; off <<= 1) s += __shfl_xor(s, off);
  if (lane == 0) ssum[w] = s;
  __syncthreads();
  if (t == 0) {
    float gs = ssum[0] + ssum[1] + ssum[2] + ssum[3];
    int tgt = ids[row];
    float tl = b2f(p[tgt]);
    rowbuf[row * 2] = gm + logf(gs) - tl;          // CE
    rowbuf[row * 2 + 1] = (gi == tgt) ? 1.f : 0.f; // correct
  }
}

// ---------- final: masked mean loss + accuracy ----------
__global__ __launch_bounds__(256) void final_reduce(const float* __restrict__ rowbuf,
                                                    const float* __restrict__ loss_mask,
                                                    float* __restrict__ out) {
  int t = threadIdx.x;
  float ce = 0.f, cnt = 0.f, cor = 0.f;
  for (int r = t; r < L; r += 256) {
    bool valid = (r >= 16) && ((r & 15) != 0);
    float comb = loss_mask[r] * (valid ? 1.f : 0.f);
    if (comb > 1e-6f) {
      ce += rowbuf[r * 2];
      cor += rowbuf[r * 2 + 1];
      cnt += 1.f;
    }
  }
  for (int off = 1; off < 64; off <<= 1) {
    ce += __shfl_xor(ce, off);
    cnt += __shfl_xor(cnt, off);
    cor += __shfl_xor(cor, off);
  }
  __shared__ float s1[4], s2[4], s3[4];
  int lane = t & 63, w = t >> 6;
  if (lane == 0) { s1[w] = ce; s2[w] = cnt; s3[w] = cor; }
  __syncthreads();
  if (t == 0) {
    float C = s1[0] + s1[1] + s1[2] + s1[3];
    float N = s2[0] + s2[1] + s2[2] + s2[3];
    float R = s3[0] + s3[1] + s3[2] + s3[3];
    out[0] = C / N;
    out[1] = R / N;
  }
}

__global__ void ws_too_small(float* out, float mb) {
  if (threadIdx.x == 0) { out[0] = 1e6f + mb; out[1] = -1e6f; }
}

// ---------- launch ----------
extern "C" void kernel_launch(void* const* d_in, const int* in_sizes, int n_in,
                              void* d_out, int out_size, void* d_ws, size_t ws_size,
                              hipStream_t stream) {
  const int* ids = (const int*)d_in[0];
  const float* hs = (const float*)d_in[2];
  const float* lmask = (const float*)d_in[3];
  const float* emb = (const float*)d_in[4];
  const float* Wq = (const float*)d_in[5];
  const float* Wk = (const float*)d_in[6];
  const float* Wv = (const float*)d_in[7];
  const float* Wo = (const float*)d_in[8];
  const float* Wlm = (const float*)d_in[9];
  float* out = (float*)d_out;
  char* ws = (char*)d_ws;

  if (ws_size < (size_t)WS_NEED) {
    ws_too_small<<<1, 64, 0, stream>>>(out, (float)(ws_size >> 20));
    return;
  }

  u16* kv  = (u16*)(ws + OFF_KV);
  u16* wtq = (u16*)(ws + OFF_WTQ);
  u16* wtk = (u16*)(ws + OFF_WTK);
  u16* wtv = (u16*)(ws + OFF_WTV);
  u16* wto = (u16*)(ws + OFF_WTO);
  u16* qb  = (u16*)(ws + OFF_Q);
  u16* kb  = (u16*)(ws + OFF_K);
  u16* vt  = (u16*)(ws + OFF_VT);
  u16* ctx = (u16*)(ws + OFF_CTX);
  u16* hid = (u16*)(ws + OFF_HID);
  u16* lmt = (u16*)(ws + OFF_LMT);
  u16* lgt = (u16*)(ws + OFF_LOG);
  float* rowbuf = (float*)(ws + OFF_ROW);

  prep_kv<<<2048, 256, 0, stream>>>(hs, ids, emb, kv);
  transpose4<<<dim3(32, 32, 4), 256, 0, stream>>>(Wq, Wk, Wv, Wo, wtq, wtk, wtv, wto);
  transpose_conv<<<dim3(500, 32), 256, 0, stream>>>(Wlm, lmt, D, VOCAB);

  // fused q/k/v projection: 256^2 8-phase, B = [wtq|wtk|wtv] (N=6144), 160 live tiles
  gemm256<EPI_QKV><<<dim3(160), 512, 0, stream>>>(kv, D, wtq, D, nullptr, 0, D, 0,
                                                  qb, kb, vt);

  // fused block-masked flash attention -> ctx
  flash_attn<<<dim3(256), 256, 0, stream>>>(qb, kb, vt, ctx);

  // hidden = ctx @ Wo
  gemm128<EPI_PLAIN><<<dim3(8, 16, 1), 256, 0, stream>>>(ctx, D, 0, wto, D, 0, hid, D, 0, D);
  // logits = hidden @ lm_head  (256^2 8-phase; grid 4 x 125 = 500)
  gemm256<EPI_PLAIN><<<dim3(500), 512, 0, stream>>>(hid, D, lmt, D, lgt, VOCAB, D, 4,
                                                    nullptr, nullptr, nullptr);

  row_ce<<<1024, 256, 0, stream>>>(lgt, ids, rowbuf);
  final_reduce<<<1, 256, 0, stream>>>(rowbuf, lmask, out);
}